// Round 21
// baseline (149.567 us; speedup 1.0000x reference)
//
#include <hip/hip_runtime.h>
#include <hip/hip_bf16.h>

#define KC 512

// d_out layout (floats), reference return order:
// quantize_st[4194304], diff[1], embed_ind[65536], embed_new[32768],
// new_cluster_size[512], new_embed_avg[32768]
#define OFF_Q     0
#define OFF_DIFF  4194304
#define OFF_IND   4194305
#define OFF_ENEW  4259841
#define OFF_NCS   4292609
#define OFF_NAVG  4293121

// ws layout (floats)
#define WS_ET    0        // 32768: embed transposed [K][D] f32
#define WS_C     32768    // 512:   0.5*||e_k||^2 f32
#define WS_CNT   33280    // 512:   one-hot counts
#define WS_ESUM  33792    // 32768: embed_sum transposed [K][D]
#define WS_DIFF  66560    // 1:     sum of squared diff
#define WS_NTOT  66561    // 1:     sum of new_cluster_size
#define WS_EB    66576    // 8192 uint4 (128 KB): bf16 B-fragments, hi then lo

typedef __attribute__((ext_vector_type(8))) short bf16x8;
typedef __attribute__((ext_vector_type(4))) float f32x4;

union U4B { uint4 u; bf16x8 b; };

__device__ __forceinline__ unsigned short f2bf(float x) {
    __hip_bfloat16 h = __float2bfloat16(x);
    union { __hip_bfloat16 h; unsigned short s; } cv; cv.h = h; return cv.s;
}
__device__ __forceinline__ float bf2f(unsigned short s) {
    union { unsigned int u; float f; } cv; cv.u = ((unsigned int)s) << 16; return cv.f;
}

// Prep: Et transpose, bias, zero accumulators, and bf16-split B-fragments.
__global__ __launch_bounds__(256) void k_prep(const float* __restrict__ embed,
                                              float* __restrict__ ws) {
    int i = blockIdx.x * 256 + threadIdx.x;
    if (i < 512 + 32768 + 2) ws[WS_CNT + i] = 0.0f;   // counts, esum, diff, ntot
    if (i < 32768) {
        int k = i >> 6, d = i & 63;
        ws[WS_ET + i] = embed[d * KC + k];
    }
    if (i < 512) {
        float s = 0.0f;
        #pragma unroll
        for (int d = 0; d < 64; ++d) { float e = embed[d * KC + i]; s = fmaf(e, e, s); }
        ws[WS_C + i] = 0.5f * s;
    }
    if (i < 8192) {
        int term = i >> 12;
        int r = i & 4095;
        int ct = r >> 7, ks = (r >> 6) & 1, ln = r & 63;
        int col = ct * 16 + (ln & 15);
        int d0 = ks * 32 + ((ln >> 4) & 3) * 8;
        unsigned int w[4];
        #pragma unroll
        for (int p = 0; p < 4; ++p) {
            float x0 = embed[(d0 + 2 * p) * KC + col];
            float x1 = embed[(d0 + 2 * p + 1) * KC + col];
            unsigned short h0 = f2bf(x0), h1 = f2bf(x1);
            unsigned short o0, o1;
            if (term == 0) { o0 = h0; o1 = h1; }
            else { o0 = f2bf(x0 - bf2f(h0)); o1 = f2bf(x1 - bf2f(h1)); }
            w[p] = (unsigned int)o0 | ((unsigned int)o1 << 16);
        }
        uint4 u; u.x = w[0]; u.y = w[1]; u.z = w[2]; u.w = w[3];
        reinterpret_cast<uint4*>(ws + WS_EB)[i] = u;
    }
}

// Split-bf16 MFMA main kernel, HYBRID operand sourcing: B_hi (2 of 3 MFMA
// uses) staged in 64 KB LDS; B_lo (1 of 3) streamed from L2 (128 MB agg).
// LDS total ~70 KB -> 2 BLOCKS/CU co-resident: independent blocks overlap
// phases (one stages/epilogues while the other MFMAs) — the overlap every
// 128KB-LDS variant (1 block/CU, 85us plateau) structurally lacked.
// 512 thr = 8 waves; wave = 16 rows x 512 codes; acc[16] f32x4 (64 AGPR),
// all indices compile-time constant (rule #20). FP chain per code identical
// to rounds 11-20 -> bit-identical outputs.
__global__ __launch_bounds__(512, 2) void k_main(const float* __restrict__ input,
                                                 const float* __restrict__ embed, // [64][512]
                                                 const uint4* __restrict__ EB,
                                                 const float* __restrict__ c,
                                                 const float* __restrict__ Et,
                                                 float* __restrict__ out,
                                                 float* __restrict__ diffsum) {
    __shared__ uint4 EBh[4096];     // 64 KB: B_hi fragments only
    __shared__ float biasl[512];
    __shared__ float sb1[8][16];
    __shared__ int   sk1[8][16];
    __shared__ float sb2[8][16];
    __shared__ float sxs[8][16];

    const int t    = threadIdx.x;
    const int lane = t & 63;
    const int wave = __builtin_amdgcn_readfirstlane(t >> 6);  // 0..7
    const int l15  = lane & 15;
    const int g4   = (lane >> 4) & 3;

    // Stage B_hi (4096 contiguous uint4) + bias.
    #pragma unroll
    for (int it = 0; it < 8; ++it) EBh[t + it * 512] = EB[t + it * 512];
    if (t < 512) biasl[t] = c[t];
    __syncthreads();

    const int R0 = blockIdx.x * 128 + wave * 16;

    // A fragments (rows R0..R0+15): bf16 split + per-row ||x||^2 partial.
    bf16x8 Ah[2], Al[2];
    float px = 0.0f;
    #pragma unroll
    for (int ks = 0; ks < 2; ++ks) {
        const float* xp = input + (size_t)(R0 + l15) * 64 + ks * 32 + g4 * 8;
        float4 a = *reinterpret_cast<const float4*>(xp);
        float4 b = *reinterpret_cast<const float4*>(xp + 4);
        float vv[8] = {a.x, a.y, a.z, a.w, b.x, b.y, b.z, b.w};
        #pragma unroll
        for (int j = 0; j < 8; ++j) {
            unsigned short hi = f2bf(vv[j]);
            Ah[ks][j] = (short)hi;
            Al[ks][j] = (short)f2bf(vv[j] - bf2f(hi));
            px += vv[j] * vv[j];
        }
    }
    px += __shfl_xor(px, 16); px += __shfl_xor(px, 32);
    if (lane < 16) sxs[wave][lane] = px;

    float B1[4], B2[4]; int K1[4];
    #pragma unroll
    for (int q = 0; q < 4; ++q) { B1[q] = -3.0e38f; B2[q] = -3.0e38f; K1[q] = 0; }

    #pragma unroll 1
    for (int h = 0; h < 2; ++h) {
        f32x4 acc[16];
        #pragma unroll
        for (int ct = 0; ct < 16; ++ct) {
            float bb = biasl[(h * 16 + ct) * 16 + l15];
            f32x4 iv = {-bb, -bb, -bb, -bb};
            acc[ct] = iv;
        }
        #pragma unroll
        for (int ct = 0; ct < 16; ++ct) {     // fully unrolled: acc static
            #pragma unroll
            for (int ks = 0; ks < 2; ++ks) {
                int base = ((h * 16 + ct) * 2 + ks) * 64 + lane;
                U4B uh, ul;
                uh.u = EBh[base];          // B_hi from LDS (conflict-free)
                ul.u = EB[4096 + base];    // B_lo from L2
                acc[ct] = __builtin_amdgcn_mfma_f32_16x16x32_bf16(Ah[ks], uh.b, acc[ct], 0, 0, 0);
                acc[ct] = __builtin_amdgcn_mfma_f32_16x16x32_bf16(Ah[ks], ul.b, acc[ct], 0, 0, 0);
                acc[ct] = __builtin_amdgcn_mfma_f32_16x16x32_bf16(Al[ks], uh.b, acc[ct], 0, 0, 0);
            }
        }
        // top-2 update (h + ct ascending = k ascending, strict >)
        #pragma unroll
        for (int reg = 0; reg < 4; ++reg) {
            #pragma unroll
            for (int ct = 0; ct < 16; ++ct) {
                float s = acc[ct][reg];
                int k = (h * 16 + ct) * 16 + l15;
                if (s > B1[reg]) { B2[reg] = B1[reg]; B1[reg] = s; K1[reg] = k; }
                else if (s > B2[reg]) B2[reg] = s;
            }
        }
    }
    // cross-lane top-2 merge over the 16 col-lanes (stays within quarter-wave)
    #pragma unroll
    for (int off = 1; off < 16; off <<= 1) {
        #pragma unroll
        for (int q = 0; q < 4; ++q) {
            float vv = __shfl_xor(B1[q], off);
            int   kk = __shfl_xor(K1[q], off);
            float v2 = __shfl_xor(B2[q], off);
            if (vv > B1[q] || (vv == B1[q] && kk < K1[q])) {
                B2[q] = fmaxf(B1[q], v2); B1[q] = vv; K1[q] = kk;
            } else {
                B2[q] = fmaxf(B2[q], vv);
            }
        }
    }
    if (l15 == 0) {
        #pragma unroll
        for (int reg = 0; reg < 4; ++reg) {
            int row = g4 * 4 + reg;
            sb1[wave][row] = B1[reg]; sk1[wave][row] = K1[reg]; sb2[wave][row] = B2[reg];
        }
    }
    // same-wave LDS readback: compiler lgkm waits suffice

    float dsum = 0.0f;
    for (int r = 0; r < 16; ++r) {
        const int row = R0 + r;
        float b1 = sb1[wave][r], b2 = sb2[wave][r], xs = sxs[wave][r];
        int   k1 = sk1[wave][r];
        if (b1 - b2 < 6.0e-3f) {
            // exact f32 recheck, coalesced embed[D][K] reads; round-9 FP order
            float xv = input[(size_t)row * 64 + lane];
            float s[8];
            #pragma unroll
            for (int j = 0; j < 8; ++j) s[j] = -biasl[lane + 64 * j];
            for (int d = 0; d < 64; ++d) {
                float xd = __shfl(xv, d);
                #pragma unroll
                for (int j = 0; j < 8; ++j)
                    s[j] = fmaf(xd, embed[d * KC + lane + 64 * j], s[j]);
            }
            float bb = s[0]; int bk = lane;
            #pragma unroll
            for (int j = 1; j < 8; ++j) {
                int cc = lane + 64 * j;
                if (s[j] > bb) { bb = s[j]; bk = cc; }
            }
            #pragma unroll
            for (int off = 1; off < 64; off <<= 1) {
                float vv = __shfl_xor(bb, off);
                int   kk = __shfl_xor(bk, off);
                if (vv > bb || (vv == bb && kk < bk)) { bb = vv; bk = kk; }
            }
            k1 = bk; b1 = bb;
        }
        float e = Et[(size_t)k1 * 64 + lane];
        out[OFF_Q + (size_t)row * 64 + lane] = e;      // coalesced store
        if (lane == 0) {
            out[OFF_IND + row] = (float)k1;
            dsum += xs - 2.0f * b1;
        }
    }
    if (lane == 0) atomicAdd(diffsum, dsum);
}

// Sliced scatter-free segment sum (round-20 proven: 32 slices, ~8 us).
__global__ __launch_bounds__(256) void k_esum(const float* __restrict__ ind,
                                              const float* __restrict__ input,
                                              float* __restrict__ esum,
                                              float* __restrict__ counts) {
    __shared__ float sacc[4][64];
    __shared__ int   scnt[4];

    const int k    = blockIdx.x & 511;
    const int sl   = blockIdx.x >> 9;           // 0..31
    const int lane = threadIdx.x & 63;
    const int wv   = threadIdx.x >> 6;          // 0..3
    const float fk = (float)k;

    float accd = 0.0f;
    int cnt = 0;
    const int rbase = sl * 2048 + wv * 512;
    #pragma unroll 4
    for (int base = rbase; base < rbase + 512; base += 64) {
        float bkf = ind[base + lane];                       // coalesced, L2-hot
        unsigned long long m = __ballot(bkf == fk);
        cnt += __popcll(m);
        while (m) {
            int b = __ffsll((unsigned long long)m) - 1;
            m &= (m - 1);
            accd += input[(size_t)(base + b) * 64 + lane];  // coalesced 256B row
        }
    }
    sacc[wv][lane] = accd;
    if (lane == 0) scnt[wv] = cnt;
    __syncthreads();
    if (wv == 0) {
        float s = sacc[0][lane] + sacc[1][lane] + sacc[2][lane] + sacc[3][lane];
        atomicAdd(&esum[k * 64 + lane], s);
        if (lane == 0) atomicAdd(&counts[k], (float)(scnt[0] + scnt[1] + scnt[2] + scnt[3]));
    }
}

// new_cluster_size + its sum + diff finalize (single block).
__global__ __launch_bounds__(512) void k_ncs(const float* __restrict__ cluster_size,
                                             const float* __restrict__ ws,
                                             float* __restrict__ out,
                                             float* __restrict__ wsw) {
    __shared__ float red[512];
    int t = threadIdx.x;
    float ncs = cluster_size[t] * 0.99f + (1.0f - 0.99f) * ws[WS_CNT + t];
    out[OFF_NCS + t] = ncs;
    red[t] = ncs;
    __syncthreads();
    for (int off = 256; off > 0; off >>= 1) {
        if (t < off) red[t] += red[t + off];
        __syncthreads();
    }
    if (t == 0) {
        wsw[WS_NTOT] = red[0];
        out[OFF_DIFF] = ws[WS_DIFF] * (1.0f / 4194304.0f);
    }
}

// new_embed_avg + embed_new.
__global__ __launch_bounds__(512) void k_emb(const float* __restrict__ embed_avg,
                                             const float* __restrict__ ws,
                                             float* __restrict__ out) {
    int d = blockIdx.x;
    int t = threadIdx.x;
    float ncs = out[OFF_NCS + t];
    float ntot = ws[WS_NTOT];
    float csk = (ncs + 1e-5f) / (ntot + 512.0f * 1e-5f) * ntot;
    int idx = d * KC + t;
    float avg = embed_avg[idx] * 0.99f + (1.0f - 0.99f) * ws[WS_ESUM + t * 64 + d];
    out[OFF_NAVG + idx] = avg;
    out[OFF_ENEW + idx] = avg / csk;
}

extern "C" void kernel_launch(void* const* d_in, const int* in_sizes, int n_in,
                              void* d_out, int out_size, void* d_ws, size_t ws_size,
                              hipStream_t stream) {
    const float* input        = (const float*)d_in[0];
    const float* embed        = (const float*)d_in[1];
    const float* cluster_size = (const float*)d_in[2];
    const float* embed_avg    = (const float*)d_in[3];
    float* out = (float*)d_out;
    float* ws  = (float*)d_ws;

    k_prep<<<131, 256, 0, stream>>>(embed, ws);
    k_main<<<512, 512, 0, stream>>>(input, embed,
                                    reinterpret_cast<const uint4*>(ws + WS_EB),
                                    ws + WS_C, ws + WS_ET, out, ws + WS_DIFF);
    k_esum<<<16384, 256, 0, stream>>>(out + OFF_IND, input, ws + WS_ESUM, ws + WS_CNT);
    k_ncs<<<1, 512, 0, stream>>>(cluster_size, ws, out, ws);
    k_emb<<<64, 512, 0, stream>>>(embed_avg, ws, out);
}

// Round 22
// 111.870 us; speedup vs baseline: 1.3370x; 1.3370x over previous
//
#include <hip/hip_runtime.h>
#include <hip/hip_bf16.h>

#define KC 512

// d_out layout (floats), reference return order:
// quantize_st[4194304], diff[1], embed_ind[65536], embed_new[32768],
// new_cluster_size[512], new_embed_avg[32768]
#define OFF_Q     0
#define OFF_DIFF  4194304
#define OFF_IND   4194305
#define OFF_ENEW  4259841
#define OFF_NCS   4292609
#define OFF_NAVG  4293121

// ws layout (floats)
#define WS_ET    0        // 32768: embed transposed [K][D] f32
#define WS_C     32768    // 512:   0.5*||e_k||^2 f32
#define WS_CNT   33280    // 512:   one-hot counts
#define WS_ESUM  33792    // 32768: embed_sum transposed [K][D]
#define WS_DIFF  66560    // 1:     sum of squared diff
#define WS_NTOT  66561    // 1:     sum of new_cluster_size
#define WS_EB    66576    // 8192 uint4 (128 KB): bf16 B-fragments, hi then lo

typedef __attribute__((ext_vector_type(8))) short bf16x8;
typedef __attribute__((ext_vector_type(4))) float f32x4;

union U4B { uint4 u; bf16x8 b; };

__device__ __forceinline__ unsigned short f2bf(float x) {
    __hip_bfloat16 h = __float2bfloat16(x);
    union { __hip_bfloat16 h; unsigned short s; } cv; cv.h = h; return cv.s;
}
__device__ __forceinline__ float bf2f(unsigned short s) {
    union { unsigned int u; float f; } cv; cv.u = ((unsigned int)s) << 16; return cv.f;
}

// Prep: Et transpose, bias, zero accumulators, and bf16-split B-fragments.
__global__ __launch_bounds__(256) void k_prep(const float* __restrict__ embed,
                                              float* __restrict__ ws) {
    int i = blockIdx.x * 256 + threadIdx.x;
    if (i < 512 + 32768 + 2) ws[WS_CNT + i] = 0.0f;   // counts, esum, diff, ntot
    if (i < 32768) {
        int k = i >> 6, d = i & 63;
        ws[WS_ET + i] = embed[d * KC + k];
    }
    if (i < 512) {
        float s = 0.0f;
        #pragma unroll
        for (int d = 0; d < 64; ++d) { float e = embed[d * KC + i]; s = fmaf(e, e, s); }
        ws[WS_C + i] = 0.5f * s;
    }
    if (i < 8192) {
        int term = i >> 12;
        int r = i & 4095;
        int ct = r >> 7, ks = (r >> 6) & 1, ln = r & 63;
        int col = ct * 16 + (ln & 15);
        int d0 = ks * 32 + ((ln >> 4) & 3) * 8;
        unsigned int w[4];
        #pragma unroll
        for (int p = 0; p < 4; ++p) {
            float x0 = embed[(d0 + 2 * p) * KC + col];
            float x1 = embed[(d0 + 2 * p + 1) * KC + col];
            unsigned short h0 = f2bf(x0), h1 = f2bf(x1);
            unsigned short o0, o1;
            if (term == 0) { o0 = h0; o1 = h1; }
            else { o0 = f2bf(x0 - bf2f(h0)); o1 = f2bf(x1 - bf2f(h1)); }
            w[p] = (unsigned int)o0 | ((unsigned int)o1 << 16);
        }
        uint4 u; u.x = w[0]; u.y = w[1]; u.z = w[2]; u.w = w[3];
        reinterpret_cast<uint4*>(ws + WS_EB)[i] = u;
    }
}

// Split-bf16 MFMA main kernel (round-13/20 proven config: best measured,
// VGPR 108, zero spill). 512 thr = 8 waves; wave = 32 rows; EB staged in
// 128 KB LDS. Score = -0.5||e||^2 + Ah*Bh + Ah*Bl + Al*Bh; per-row approx
// top-2 with exact f32 recheck when gap < 6e-3 => argmin exact. All acc
// indices compile-time constant (rule #20).
__global__ __launch_bounds__(512, 2) void k_main(const float* __restrict__ input,
                                                 const float* __restrict__ embed, // [64][512]
                                                 const uint4* __restrict__ EB,
                                                 const float* __restrict__ c,
                                                 const float* __restrict__ Et,
                                                 float* __restrict__ out,
                                                 float* __restrict__ diffsum) {
    __shared__ uint4 EBl[8192];     // 128 KB
    __shared__ float biasl[512];
    __shared__ float sb1[8][32];
    __shared__ int   sk1[8][32];
    __shared__ float sb2[8][32];
    __shared__ float sxs[8][32];

    const int t    = threadIdx.x;
    const int lane = t & 63;
    const int wave = __builtin_amdgcn_readfirstlane(t >> 6);
    const int l15  = lane & 15;
    const int g4   = (lane >> 4) & 3;

    #pragma unroll
    for (int it = 0; it < 16; ++it) EBl[t + it * 512] = EB[t + it * 512];
    if (t < 512) biasl[t] = c[t];
    __syncthreads();

    const int R0 = blockIdx.x * 256 + wave * 32;

    // A fragments: load x rows, bf16-split; xs partials per row.
    bf16x8 Ah[2][2], Al[2][2];
    float px[2] = {0.0f, 0.0f};
    #pragma unroll
    for (int rt = 0; rt < 2; ++rt) {
        #pragma unroll
        for (int ks = 0; ks < 2; ++ks) {
            const float* xp = input + (size_t)(R0 + rt * 16 + l15) * 64 + ks * 32 + g4 * 8;
            float4 a = *reinterpret_cast<const float4*>(xp);
            float4 b = *reinterpret_cast<const float4*>(xp + 4);
            float vv[8] = {a.x, a.y, a.z, a.w, b.x, b.y, b.z, b.w};
            #pragma unroll
            for (int j = 0; j < 8; ++j) {
                unsigned short hi = f2bf(vv[j]);
                Ah[rt][ks][j] = (short)hi;
                Al[rt][ks][j] = (short)f2bf(vv[j] - bf2f(hi));
                px[rt] += vv[j] * vv[j];
            }
        }
    }
    px[0] += __shfl_xor(px[0], 16); px[0] += __shfl_xor(px[0], 32);
    px[1] += __shfl_xor(px[1], 16); px[1] += __shfl_xor(px[1], 32);
    if (lane < 16) { sxs[wave][lane] = px[0]; sxs[wave][16 + lane] = px[1]; }

    float B1[8], B2[8]; int K1[8];
    #pragma unroll
    for (int q = 0; q < 8; ++q) { B1[q] = -3.0e38f; B2[q] = -3.0e38f; K1[q] = 0; }

    for (int h = 0; h < 2; ++h) {
        f32x4 acc[2][16];
        #pragma unroll
        for (int ct = 0; ct < 16; ++ct) {
            float bb = biasl[(h * 16 + ct) * 16 + l15];
            f32x4 iv = {-bb, -bb, -bb, -bb};
            acc[0][ct] = iv; acc[1][ct] = iv;
        }
        #pragma unroll
        for (int ct = 0; ct < 16; ++ct) {
            #pragma unroll
            for (int ks = 0; ks < 2; ++ks) {
                int base = ((h * 16 + ct) * 2 + ks) * 64 + lane;
                U4B uh, ul;
                uh.u = EBl[base];          // B_hi
                ul.u = EBl[4096 + base];   // B_lo
                #pragma unroll
                for (int rt = 0; rt < 2; ++rt)
                    acc[rt][ct] = __builtin_amdgcn_mfma_f32_16x16x32_bf16(Ah[rt][ks], uh.b, acc[rt][ct], 0, 0, 0);
                #pragma unroll
                for (int rt = 0; rt < 2; ++rt)
                    acc[rt][ct] = __builtin_amdgcn_mfma_f32_16x16x32_bf16(Ah[rt][ks], ul.b, acc[rt][ct], 0, 0, 0);
                #pragma unroll
                for (int rt = 0; rt < 2; ++rt)
                    acc[rt][ct] = __builtin_amdgcn_mfma_f32_16x16x32_bf16(Al[rt][ks], uh.b, acc[rt][ct], 0, 0, 0);
            }
        }
        #pragma unroll
        for (int rt = 0; rt < 2; ++rt) {
            #pragma unroll
            for (int reg = 0; reg < 4; ++reg) {
                int q = rt * 4 + reg;
                #pragma unroll
                for (int ct = 0; ct < 16; ++ct) {
                    float s = acc[rt][ct][reg];
                    int k = (h * 16 + ct) * 16 + l15;
                    if (s > B1[q]) { B2[q] = B1[q]; B1[q] = s; K1[q] = k; }
                    else if (s > B2[q]) B2[q] = s;
                }
            }
        }
    }
    // cross-lane top-2 merge over the 16 col-lanes
    #pragma unroll
    for (int off = 1; off < 16; off <<= 1) {
        #pragma unroll
        for (int q = 0; q < 8; ++q) {
            float vv = __shfl_xor(B1[q], off);
            int   kk = __shfl_xor(K1[q], off);
            float v2 = __shfl_xor(B2[q], off);
            if (vv > B1[q] || (vv == B1[q] && kk < K1[q])) {
                B2[q] = fmaxf(B1[q], v2); B1[q] = vv; K1[q] = kk;
            } else {
                B2[q] = fmaxf(B2[q], vv);
            }
        }
    }
    if (l15 == 0) {
        #pragma unroll
        for (int rt = 0; rt < 2; ++rt)
            #pragma unroll
            for (int reg = 0; reg < 4; ++reg) {
                int row = rt * 16 + g4 * 4 + reg, q = rt * 4 + reg;
                sb1[wave][row] = B1[q]; sk1[wave][row] = K1[q]; sb2[wave][row] = B2[q];
            }
    }
    // same-wave LDS readback: compiler lgkm waits suffice

    float dsum = 0.0f;
    for (int r = 0; r < 32; ++r) {
        const int row = R0 + r;
        float b1 = sb1[wave][r], b2 = sb2[wave][r], xs = sxs[wave][r];
        int   k1 = sk1[wave][r];
        if (b1 - b2 < 6.0e-3f) {
            // exact f32 recheck, COALESCED embed[D][K] reads; round-9 FP order
            float xv = input[(size_t)row * 64 + lane];
            float s[8];
            #pragma unroll
            for (int j = 0; j < 8; ++j) s[j] = -biasl[lane + 64 * j];
            for (int d = 0; d < 64; ++d) {
                float xd = __shfl(xv, d);
                #pragma unroll
                for (int j = 0; j < 8; ++j)
                    s[j] = fmaf(xd, embed[d * KC + lane + 64 * j], s[j]);
            }
            float bb = s[0]; int bk = lane;
            #pragma unroll
            for (int j = 1; j < 8; ++j) {
                int cc = lane + 64 * j;
                if (s[j] > bb) { bb = s[j]; bk = cc; }
            }
            #pragma unroll
            for (int off = 1; off < 64; off <<= 1) {
                float vv = __shfl_xor(bb, off);
                int   kk = __shfl_xor(bk, off);
                if (vv > bb || (vv == bb && kk < bk)) { bb = vv; bk = kk; }
            }
            k1 = bk; b1 = bb;
        }
        float e = Et[(size_t)k1 * 64 + lane];
        out[OFF_Q + (size_t)row * 64 + lane] = e;      // coalesced store
        if (lane == 0) {
            out[OFF_IND + row] = (float)k1;
            dsum += xs - 2.0f * b1;
        }
    }
    if (lane == 0) atomicAdd(diffsum, dsum);
}

// Sliced scatter-free segment sum (round-20 proven: 32 slices).
// Grid = 512 codes x 32 slices = 16384 blocks.
__global__ __launch_bounds__(256) void k_esum(const float* __restrict__ ind,
                                              const float* __restrict__ input,
                                              float* __restrict__ esum,
                                              float* __restrict__ counts) {
    __shared__ float sacc[4][64];
    __shared__ int   scnt[4];

    const int k    = blockIdx.x & 511;
    const int sl   = blockIdx.x >> 9;           // 0..31
    const int lane = threadIdx.x & 63;
    const int wv   = threadIdx.x >> 6;          // 0..3
    const float fk = (float)k;

    float accd = 0.0f;
    int cnt = 0;
    const int rbase = sl * 2048 + wv * 512;
    #pragma unroll 4
    for (int base = rbase; base < rbase + 512; base += 64) {
        float bkf = ind[base + lane];                       // coalesced, L2-hot
        unsigned long long m = __ballot(bkf == fk);
        cnt += __popcll(m);
        while (m) {
            int b = __ffsll((unsigned long long)m) - 1;
            m &= (m - 1);
            accd += input[(size_t)(base + b) * 64 + lane];  // coalesced 256B row
        }
    }
    sacc[wv][lane] = accd;
    if (lane == 0) scnt[wv] = cnt;
    __syncthreads();
    if (wv == 0) {
        float s = sacc[0][lane] + sacc[1][lane] + sacc[2][lane] + sacc[3][lane];
        atomicAdd(&esum[k * 64 + lane], s);
        if (lane == 0) atomicAdd(&counts[k], (float)(scnt[0] + scnt[1] + scnt[2] + scnt[3]));
    }
}

// new_cluster_size + its sum + diff finalize (single block).
__global__ __launch_bounds__(512) void k_ncs(const float* __restrict__ cluster_size,
                                             const float* __restrict__ ws,
                                             float* __restrict__ out,
                                             float* __restrict__ wsw) {
    __shared__ float red[512];
    int t = threadIdx.x;
    float ncs = cluster_size[t] * 0.99f + (1.0f - 0.99f) * ws[WS_CNT + t];
    out[OFF_NCS + t] = ncs;
    red[t] = ncs;
    __syncthreads();
    for (int off = 256; off > 0; off >>= 1) {
        if (t < off) red[t] += red[t + off];
        __syncthreads();
    }
    if (t == 0) {
        wsw[WS_NTOT] = red[0];
        out[OFF_DIFF] = ws[WS_DIFF] * (1.0f / 4194304.0f);
    }
}

// new_embed_avg + embed_new.
__global__ __launch_bounds__(512) void k_emb(const float* __restrict__ embed_avg,
                                             const float* __restrict__ ws,
                                             float* __restrict__ out) {
    int d = blockIdx.x;
    int t = threadIdx.x;
    float ncs = out[OFF_NCS + t];
    float ntot = ws[WS_NTOT];
    float csk = (ncs + 1e-5f) / (ntot + 512.0f * 1e-5f) * ntot;
    int idx = d * KC + t;
    float avg = embed_avg[idx] * 0.99f + (1.0f - 0.99f) * ws[WS_ESUM + t * 64 + d];
    out[OFF_NAVG + idx] = avg;
    out[OFF_ENEW + idx] = avg / csk;
}

extern "C" void kernel_launch(void* const* d_in, const int* in_sizes, int n_in,
                              void* d_out, int out_size, void* d_ws, size_t ws_size,
                              hipStream_t stream) {
    const float* input        = (const float*)d_in[0];
    const float* embed        = (const float*)d_in[1];
    const float* cluster_size = (const float*)d_in[2];
    const float* embed_avg    = (const float*)d_in[3];
    float* out = (float*)d_out;
    float* ws  = (float*)d_ws;

    k_prep<<<131, 256, 0, stream>>>(embed, ws);
    k_main<<<256, 512, 0, stream>>>(input, embed,
                                    reinterpret_cast<const uint4*>(ws + WS_EB),
                                    ws + WS_C, ws + WS_ET, out, ws + WS_DIFF);
    k_esum<<<16384, 256, 0, stream>>>(out + OFF_IND, input, ws + WS_ESUM, ws + WS_CNT);
    k_ncs<<<1, 512, 0, stream>>>(cluster_size, ws, out, ws);
    k_emb<<<64, 512, 0, stream>>>(embed_avg, ws, out);
}